// Round 6
// baseline (377.329 us; speedup 1.0000x reference)
//
#include <hip/hip_runtime.h>

typedef unsigned short ushort_t;
typedef __bf16 bf16x8 __attribute__((ext_vector_type(8)));
typedef float f32x4 __attribute__((ext_vector_type(4)));

// f32 -> bf16 bits, round-to-nearest-even
__device__ inline ushort_t f2bf(float f) {
  unsigned int u = __builtin_bit_cast(unsigned int, f);
  u += 0x7fff + ((u >> 16) & 1);
  return (ushort_t)(u >> 16);
}

// pack two f32 -> bf16x2 (RNE), b in high half
__device__ inline unsigned pk_bf(float a, float b) {
  unsigned ua = __builtin_bit_cast(unsigned, a);
  unsigned ub = __builtin_bit_cast(unsigned, b);
  ua += 0x7fff + ((ua >> 16) & 1);
  ub += 0x7fff + ((ub >> 16) & 1);
  return __builtin_amdgcn_perm(ub, ua, 0x07060302);
}

// async global->LDS, 16B per lane; LDS dest = wave-uniform base + lane*16B
__device__ inline void async_ld16(const ushort_t* g, const ushort_t* l) {
  __builtin_amdgcn_global_load_lds(
      (const __attribute__((address_space(1))) void*)g,
      (__attribute__((address_space(3))) void*)l, 16, 0, 0);
}

// Fine-grained pipeline barrier: wait for all but the newest N vmem ops,
// then workgroup barrier. IMM encodes vmcnt(N): 0x0F70|N, lgkm=15, exp=7.
template <int IMM>
__device__ inline void waitcnt_barrier() {
  asm volatile("" ::: "memory");
  __builtin_amdgcn_s_waitcnt(IMM);
  __builtin_amdgcn_s_barrier();
  asm volatile("" ::: "memory");
}

// one fused conversion kernel: x (1048576 f4) | Wa (786432 f4) | Wp (262144 f4)
__global__ void cvt_all(const float* __restrict__ x, const float* __restrict__ wa,
                        const float* __restrict__ wp, ushort_t* __restrict__ xb,
                        ushort_t* __restrict__ wab, ushort_t* __restrict__ wpb) {
  int i = blockIdx.x * 256 + threadIdx.x;
  const float* src;
  ushort_t* dst;
  int off;
  if (i < 1048576) { src = x; dst = xb; off = i; }
  else if (i < 1835008) { src = wa; dst = wab; off = i - 1048576; }
  else { src = wp; dst = wpb; off = i - 1835008; }
  float4 f = ((const float4*)src)[off];
  unsigned long long p = (unsigned long long)f2bf(f.x)
      | ((unsigned long long)f2bf(f.y) << 16)
      | ((unsigned long long)f2bf(f.z) << 32)
      | ((unsigned long long)f2bf(f.w) << 48);
  ((unsigned long long*)dst)[off] = p;
}

// C[m][n] = sum_k A[m][k]*B[n][k] + bias[n]; A:[M,K] bf16, B:[N,K] bf16.
// BK=32, TRIPLE-buffered LDS, depth-2 prefetch, manual vmcnt barriers.
template <int BM, int BN, int IM, int JN, int MODE>
__global__ __launch_bounds__(256) void gemm_bt(
    const ushort_t* __restrict__ A, const ushort_t* __restrict__ B,
    const float* __restrict__ bias, float* __restrict__ Cf,
    ushort_t* __restrict__ Cb, ushort_t* __restrict__ vtb,
    int M, int N, int K, int ldc, float qscale) {
  constexpr int NWN = BN / (JN * 16);
  constexpr int NL = (BM + BN) / 64;     // vmem loads per thread per stage
  constexpr int WIMM = 0x0F70 | NL;      // vmcnt(NL), no lgkm/exp wait
  __shared__ __align__(16) ushort_t As[3][BM * 32];
  __shared__ __align__(16) ushort_t Bs[3][BN * 32];
  const int tid = threadIdx.x;
  const int wave = tid >> 6, lane = tid & 63;
  const int quad = lane >> 4, l16 = lane & 15;
  const int wr = wave / NWN, wc = wave % NWN;
  const int wm = wr * IM * 16, wn = wc * JN * 16;
  const int m0 = blockIdx.y * BM, n0 = blockIdx.x * BN;
  const ushort_t* Ag = A + (size_t)m0 * K;
  const ushort_t* Bg = B + (size_t)n0 * K;
  const int slot = (quad ^ ((l16 >> 1) & 3)) * 8;
  f32x4 acc[IM][JN] = {};

  auto stage = [&](int kt, int bsel) {
    int k0 = kt * 32;
#pragma unroll
    for (int p = 0; p < BM / 64; ++p) {
      int ci = p * 256 + tid;
      int row = ci >> 2, ch = (ci & 3) ^ ((ci >> 3) & 3);
      async_ld16(Ag + (size_t)row * K + k0 + ch * 8, As[bsel] + (p * 256 + wave * 64) * 8);
    }
#pragma unroll
    for (int p = 0; p < BN / 64; ++p) {
      int ci = p * 256 + tid;
      int row = ci >> 2, ch = (ci & 3) ^ ((ci >> 3) & 3);
      async_ld16(Bg + (size_t)row * K + k0 + ch * 8, Bs[bsel] + (p * 256 + wave * 64) * 8);
    }
  };

  const int KT = K / 32;
  stage(0, 0);
  stage(1, 1);
  for (int kt = 0; kt < KT; ++kt) {
    waitcnt_barrier<WIMM>();  // stage(kt) landed; stage(kt+1) still in flight
    if (kt + 2 < KT) stage(kt + 2, (kt + 2) % 3);
    const ushort_t* Ac = As[kt % 3];
    const ushort_t* Bc = Bs[kt % 3];
    bf16x8 af[IM], bfr[JN];
#pragma unroll
    for (int i = 0; i < IM; ++i)
      af[i] = *(const bf16x8*)(Ac + (wm + i * 16 + l16) * 32 + slot);
#pragma unroll
    for (int j = 0; j < JN; ++j)
      bfr[j] = *(const bf16x8*)(Bc + (wn + j * 16 + l16) * 32 + slot);
#pragma unroll
    for (int i = 0; i < IM; ++i)
#pragma unroll
      for (int j = 0; j < JN; ++j)
        acc[i][j] = __builtin_amdgcn_mfma_f32_16x16x32_bf16(af[i], bfr[j], acc[i][j], 0, 0, 0);
  }

  if (MODE == 1 && n0 >= 2048) {
    // V third: write transposed packed to vtb[(b*16+h)*64+d][t]
#pragma unroll
    for (int j = 0; j < JN; ++j) {
      int col = n0 + wn + j * 16 + l16;
      int cv = col - 2048;
      float bv = bias[col];
      size_t rowbase = ((size_t)(cv >> 6)) * 64 + (cv & 63);  // (h*64+d) within batch
#pragma unroll
      for (int i = 0; i < IM; ++i) {
        int rowb = m0 + wm + i * 16 + quad * 4;
        int bb = rowb >> 11, t = rowb & 2047;
        uint2 pp;
        pp.x = pk_bf(acc[i][j][0] + bv, acc[i][j][1] + bv);
        pp.y = pk_bf(acc[i][j][2] + bv, acc[i][j][3] + bv);
        *(uint2*)(vtb + (((size_t)bb * 1024 + rowbase) * 2048 + t)) = pp;
      }
    }
    return;
  }
#pragma unroll
  for (int j = 0; j < JN; ++j) {
    int col = n0 + wn + j * 16 + l16;
    float bv = bias[col];
    float sc = (MODE == 1 && col < 1024) ? qscale : 1.0f;
#pragma unroll
    for (int i = 0; i < IM; ++i)
#pragma unroll
      for (int r = 0; r < 4; ++r) {
        int row = m0 + wm + i * 16 + quad * 4 + r;
        float v = (acc[i][j][r] + bv) * sc;
        if (MODE == 1)
          Cb[(size_t)row * ldc + col] = f2bf(v);
        else
          Cf[(size_t)row * ldc + col] = v;
      }
  }
}

// BARRIER-FREE register flash attention, causal, exp2 basis, static max.
// K/V/Q MFMA fragments loaded directly global->VGPR (L2-resident; no LDS
// staging, no __syncthreads anywhere). Ps is wave-private LDS (P^T C->B
// layout round-trip). l-reduction deferred to epilogue (static max => pure
// accumulation). One block per (q-tile of 64, bh); LPT: qt = 31-blockIdx.x.
// S^T = K*Q^T (rows=key, cols=q), O^T = V^T*P^T (rows=d, cols=q).
__global__ __launch_bounds__(256) void flash3(
    const ushort_t* __restrict__ qk, const ushort_t* __restrict__ vt,
    ushort_t* __restrict__ y) {
  __shared__ __align__(16) ushort_t Ps[4][16 * 72];  // per-wave private
  const int tid = threadIdx.x, wave = tid >> 6, lane = tid & 63;
  const int quad = lane >> 4, l16 = lane & 15;
  const int qt = 31 - blockIdx.x;  // LPT
  const int bh = blockIdx.y;
  const int b = bh >> 4, h = bh & 15;
  const int bT = b * 2048;
  const int q0 = qt * 64;
  ushort_t* Pw = Ps[wave];

  // Q B-fragments straight from global (row = this wave's q, col chunk = quad)
  const ushort_t* qrow = qk + (size_t)(bT + q0 + wave * 16 + l16) * 2048 + h * 64 + quad * 8;
  bf16x8 qf[2];
  qf[0] = *(const bf16x8*)(qrow);
  qf[1] = *(const bf16x8*)(qrow + 32);

  // K/V fragment row pointers (advance by 64 rows / 64 cols per tile)
  const ushort_t* kp[4];
  const ushort_t* vp[4];
#pragma unroll
  for (int j = 0; j < 4; ++j) {
    kp[j] = qk + (size_t)(bT + j * 16 + l16) * 2048 + 1024 + h * 64 + quad * 8;
    vp[j] = vt + (size_t)(bh * 64 + j * 16 + l16) * 2048 + quad * 8;
  }

  f32x4 o[4] = {};
  float lacc = 0.f;

  for (int kt = 0; kt <= qt; ++kt) {
    // K fragments (A-operand: m=key=j*16+l16, k=dim quad*8+ks*32)
    bf16x8 kf[4][2];
#pragma unroll
    for (int j = 0; j < 4; ++j) {
      kf[j][0] = *(const bf16x8*)(kp[j]);
      kf[j][1] = *(const bf16x8*)(kp[j] + 32);
    }
    f32x4 s[4] = {};
#pragma unroll
    for (int ks = 0; ks < 2; ++ks)
#pragma unroll
      for (int j = 0; j < 4; ++j)
        s[j] = __builtin_amdgcn_mfma_f32_16x16x32_bf16(kf[j][ks], qf[ks], s[j], 0, 0, 0);
    // V fragments issued now; land during softmax
    bf16x8 vf[4][2];
#pragma unroll
    for (int j = 0; j < 4; ++j) {
      vf[j][0] = *(const bf16x8*)(vp[j]);
      vf[j][1] = *(const bf16x8*)(vp[j] + 32);
      kp[j] += 64 * 2048;
      vp[j] += 64;
    }
    if (kt == qt) {  // causal mask on diagonal tile
      int qloc = wave * 16 + l16;
#pragma unroll
      for (int j = 0; j < 4; ++j)
#pragma unroll
        for (int r = 0; r < 4; ++r)
          if (j * 16 + quad * 4 + r > qloc) s[j][r] = -1e30f;
    }
    // static-max softmax: P = exp2(s); per-lane partial row-sum (no shfl)
#pragma unroll
    for (int j = 0; j < 4; ++j)
#pragma unroll
      for (int r = 0; r < 4; ++r) {
        float pv = exp2f(s[j][r]);
        s[j][r] = pv;
        lacc += pv;
      }
    // P^T C-layout -> wave-private LDS -> B-layout fragments
#pragma unroll
    for (int j = 0; j < 4; ++j) {
      uint2 pp;
      pp.x = pk_bf(s[j][0], s[j][1]);
      pp.y = pk_bf(s[j][2], s[j][3]);
      *(uint2*)(Pw + l16 * 72 + j * 16 + quad * 4) = pp;
    }
    __builtin_amdgcn_s_waitcnt(0xc07f);  // lgkmcnt(0): own-wave visibility
    bf16x8 pf[2];
    pf[0] = *(const bf16x8*)(Pw + l16 * 72 + quad * 8);
    pf[1] = *(const bf16x8*)(Pw + l16 * 72 + 32 + quad * 8);
#pragma unroll
    for (int ks = 0; ks < 2; ++ks)
#pragma unroll
      for (int j = 0; j < 4; ++j)
        o[j] = __builtin_amdgcn_mfma_f32_16x16x32_bf16(vf[j][ks], pf[ks], o[j], 0, 0, 0);
  }

  // deferred l reduction across the 4 quads holding the same q
  lacc += __shfl_xor(lacc, 16, 64);
  lacc += __shfl_xor(lacc, 32, 64);
  float inv = 1.f / lacc;
  size_t row = (size_t)(bT + q0 + wave * 16 + l16);
#pragma unroll
  for (int j = 0; j < 4; ++j) {
    uint2 pp;
    pp.x = pk_bf(o[j][0] * inv, o[j][1] * inv);
    pp.y = pk_bf(o[j][2] * inv, o[j][3] * inv);
    *(uint2*)(y + row * 1024 + h * 64 + j * 16 + quad * 4) = pp;
  }
}

extern "C" void kernel_launch(void* const* d_in, const int* in_sizes, int n_in,
                              void* d_out, int out_size, void* d_ws, size_t ws_size,
                              hipStream_t stream) {
  const float* x  = (const float*)d_in[0];
  const float* Wa = (const float*)d_in[1];
  const float* ba = (const float*)d_in[2];
  const float* Wp = (const float*)d_in[3];
  const float* bp = (const float*)d_in[4];
  float* out = (float*)d_out;
  char* ws = (char*)d_ws;
  // ws layout (bytes): xb 8.39M | Wab 6.29M | Wpb 2.10M | qk 16.78M | yb 8.39M | vt 8.39M
  ushort_t* xb  = (ushort_t*)(ws);
  ushort_t* Wab = (ushort_t*)(ws + 8388608);
  ushort_t* Wpb = (ushort_t*)(ws + 14680064);
  ushort_t* qkb = (ushort_t*)(ws + 16777216);
  ushort_t* yb  = (ushort_t*)(ws + 33554432);
  ushort_t* vtb = (ushort_t*)(ws + 41943040);

  cvt_all<<<8192, 256, 0, stream>>>(x, Wa, Wp, xb, Wab, Wpb);
  // qkv = x @ W_attn^T + b_attn; Q scaled by 0.125*log2(e); V written transposed
  gemm_bt<128, 128, 4, 4, 1><<<dim3(24, 32), 256, 0, stream>>>(
      xb, Wab, ba, nullptr, qkb, vtb, 4096, 3072, 1024, 2048, 0.18033688011112042f);
  // flash attention -> yb [4096,1024] bf16 (1024 independent blocks, no barriers)
  flash3<<<dim3(32, 32), 256, 0, stream>>>(qkb, vtb, yb);
  // out = yb @ W_proj^T + b_proj  [4096,1024] f32  (64x64 tiles -> 1024 blocks)
  gemm_bt<64, 64, 2, 2, 0><<<dim3(16, 64), 256, 0, stream>>>(
      yb, Wpb, bp, out, nullptr, nullptr, 4096, 1024, 1024, 1024, 1.0f);
}

// Round 7
// 239.216 us; speedup vs baseline: 1.5774x; 1.5774x over previous
//
#include <hip/hip_runtime.h>

typedef unsigned short ushort_t;
typedef __bf16 bf16x8 __attribute__((ext_vector_type(8)));
typedef float f32x4 __attribute__((ext_vector_type(4)));

// f32 -> bf16 bits, round-to-nearest-even
__device__ inline ushort_t f2bf(float f) {
  unsigned int u = __builtin_bit_cast(unsigned int, f);
  u += 0x7fff + ((u >> 16) & 1);
  return (ushort_t)(u >> 16);
}

// pack two f32 -> bf16x2 (RNE), b in high half
__device__ inline unsigned pk_bf(float a, float b) {
  unsigned ua = __builtin_bit_cast(unsigned, a);
  unsigned ub = __builtin_bit_cast(unsigned, b);
  ua += 0x7fff + ((ua >> 16) & 1);
  ub += 0x7fff + ((ub >> 16) & 1);
  return __builtin_amdgcn_perm(ub, ua, 0x07060302);
}

// async global->LDS, 16B per lane; LDS dest = wave-uniform base + lane*16B
__device__ inline void async_ld16(const ushort_t* g, const ushort_t* l) {
  __builtin_amdgcn_global_load_lds(
      (const __attribute__((address_space(1))) void*)g,
      (__attribute__((address_space(3))) void*)l, 16, 0, 0);
}

// Fine-grained pipeline barrier: wait for all but the newest N vmem ops,
// then workgroup barrier. IMM encodes vmcnt(N): 0x0F70|N, lgkm=15, exp=7.
template <int IMM>
__device__ inline void waitcnt_barrier() {
  asm volatile("" ::: "memory");
  __builtin_amdgcn_s_waitcnt(IMM);
  __builtin_amdgcn_s_barrier();
  asm volatile("" ::: "memory");
}

// one fused conversion kernel: x (1048576 f4) | Wa (786432 f4) | Wp (262144 f4)
__global__ void cvt_all(const float* __restrict__ x, const float* __restrict__ wa,
                        const float* __restrict__ wp, ushort_t* __restrict__ xb,
                        ushort_t* __restrict__ wab, ushort_t* __restrict__ wpb) {
  int i = blockIdx.x * 256 + threadIdx.x;
  const float* src;
  ushort_t* dst;
  int off;
  if (i < 1048576) { src = x; dst = xb; off = i; }
  else if (i < 1835008) { src = wa; dst = wab; off = i - 1048576; }
  else { src = wp; dst = wpb; off = i - 1835008; }
  float4 f = ((const float4*)src)[off];
  unsigned long long p = (unsigned long long)f2bf(f.x)
      | ((unsigned long long)f2bf(f.y) << 16)
      | ((unsigned long long)f2bf(f.z) << 32)
      | ((unsigned long long)f2bf(f.w) << 48);
  ((unsigned long long*)dst)[off] = p;
}

// C[m][n] = sum_k A[m][k]*B[n][k] + bias[n]; A:[M,K] bf16, B:[N,K] bf16.
// BK=32, TRIPLE-buffered LDS, depth-2 prefetch, manual vmcnt barriers.
// TPB threads (256 or 512); wave (wr,wc) computes IM*16 x JN*16.
template <int BM, int BN, int IM, int JN, int MODE, int TPB>
__global__ __launch_bounds__(TPB) void gemm_bt(
    const ushort_t* __restrict__ A, const ushort_t* __restrict__ B,
    const float* __restrict__ bias, float* __restrict__ Cf,
    ushort_t* __restrict__ Cb, ushort_t* __restrict__ vtb,
    int M, int N, int K, int ldc, float qscale) {
  constexpr int NWN = BN / (JN * 16);
  constexpr int NL = (BM + BN) * 32 / (TPB * 8);  // vmem loads/thread/stage
  constexpr int WIMM = 0x0F70 | NL;               // vmcnt(NL)
  __shared__ __align__(16) ushort_t As[3][BM * 32];
  __shared__ __align__(16) ushort_t Bs[3][BN * 32];
  const int tid = threadIdx.x;
  const int wave = tid >> 6, lane = tid & 63;
  const int quad = lane >> 4, l16 = lane & 15;
  const int wr = wave / NWN, wc = wave % NWN;
  const int wm = wr * IM * 16, wn = wc * JN * 16;
  const int m0 = blockIdx.y * BM, n0 = blockIdx.x * BN;
  const ushort_t* Ag = A + (size_t)m0 * K;
  const ushort_t* Bg = B + (size_t)n0 * K;
  const int slot = (quad ^ ((l16 >> 1) & 3)) * 8;
  f32x4 acc[IM][JN] = {};

  auto stage = [&](int kt, int bsel) {
    int k0 = kt * 32;
#pragma unroll
    for (int p = 0; p < BM * 4 / TPB; ++p) {
      int ci = p * TPB + tid;
      int row = ci >> 2, ch = (ci & 3) ^ ((ci >> 3) & 3);
      async_ld16(Ag + (size_t)row * K + k0 + ch * 8, As[bsel] + (p * TPB + wave * 64) * 8);
    }
#pragma unroll
    for (int p = 0; p < BN * 4 / TPB; ++p) {
      int ci = p * TPB + tid;
      int row = ci >> 2, ch = (ci & 3) ^ ((ci >> 3) & 3);
      async_ld16(Bg + (size_t)row * K + k0 + ch * 8, Bs[bsel] + (p * TPB + wave * 64) * 8);
    }
  };

  const int KT = K / 32;
  stage(0, 0);
  stage(1, 1);
  for (int kt = 0; kt < KT; ++kt) {
    waitcnt_barrier<WIMM>();  // stage(kt) landed; stage(kt+1) still in flight
    if (kt + 2 < KT) stage(kt + 2, (kt + 2) % 3);
    const ushort_t* Ac = As[kt % 3];
    const ushort_t* Bc = Bs[kt % 3];
    bf16x8 af[IM], bfr[JN];
#pragma unroll
    for (int i = 0; i < IM; ++i)
      af[i] = *(const bf16x8*)(Ac + (wm + i * 16 + l16) * 32 + slot);
#pragma unroll
    for (int j = 0; j < JN; ++j)
      bfr[j] = *(const bf16x8*)(Bc + (wn + j * 16 + l16) * 32 + slot);
#pragma unroll
    for (int i = 0; i < IM; ++i)
#pragma unroll
      for (int j = 0; j < JN; ++j)
        acc[i][j] = __builtin_amdgcn_mfma_f32_16x16x32_bf16(af[i], bfr[j], acc[i][j], 0, 0, 0);
  }

  if (MODE == 1 && n0 >= 2048) {
    // V third: write transposed packed to vtb[(b*16+h)*64+d][t]
#pragma unroll
    for (int j = 0; j < JN; ++j) {
      int col = n0 + wn + j * 16 + l16;
      int cv = col - 2048;
      float bv = bias[col];
      size_t rowbase = ((size_t)(cv >> 6)) * 64 + (cv & 63);  // (h*64+d) within batch
#pragma unroll
      for (int i = 0; i < IM; ++i) {
        int rowb = m0 + wm + i * 16 + quad * 4;
        int bb = rowb >> 11, t = rowb & 2047;
        uint2 pp;
        pp.x = pk_bf(acc[i][j][0] + bv, acc[i][j][1] + bv);
        pp.y = pk_bf(acc[i][j][2] + bv, acc[i][j][3] + bv);
        *(uint2*)(vtb + (((size_t)bb * 1024 + rowbase) * 2048 + t)) = pp;
      }
    }
    return;
  }
#pragma unroll
  for (int j = 0; j < JN; ++j) {
    int col = n0 + wn + j * 16 + l16;
    float bv = bias[col];
    float sc = (MODE == 1 && col < 1024) ? qscale : 1.0f;
#pragma unroll
    for (int i = 0; i < IM; ++i)
#pragma unroll
      for (int r = 0; r < 4; ++r) {
        int row = m0 + wm + i * 16 + quad * 4 + r;
        float v = (acc[i][j][r] + bv) * sc;
        if (MODE == 1)
          Cb[(size_t)row * ldc + col] = f2bf(v);
        else
          Cf[(size_t)row * ldc + col] = v;
      }
  }
}

// Transposed flash attention, causal, exp2 basis, static max. Paired q-tiles
// (p, 31-p) with the pair FUSED into one body per iteration: shared K frag
// loads, S-MFMAs for both tiles, ONE lgkmcnt(0) for both P round-trips, both
// PV-MFMAs. Triple-buffered K/V, depth-2 prefetch, vmcnt barriers.
// S^T = K*Q^T (rows=key, cols=q), O^T = V^T*P^T (rows=d, cols=q).
__global__ __launch_bounds__(256) void flash4(
    const ushort_t* __restrict__ qk, const ushort_t* __restrict__ vt,
    ushort_t* __restrict__ y) {
  __shared__ __align__(16) ushort_t Kb[3][4096];
  __shared__ __align__(16) ushort_t Vb[3][4096];
  __shared__ __align__(16) ushort_t Qa[4096], Qb[4096];
  __shared__ __align__(16) ushort_t Ps[8][16 * 72];  // [wave] A, [wave+4] B
  const int tid = threadIdx.x, wave = tid >> 6, lane = tid & 63;
  const int quad = lane >> 4, l16 = lane & 15;
  const int r7 = l16 & 7;
  const int p = blockIdx.x, bh = blockIdx.y;
  const int b = bh >> 4, h = bh & 15;
  const int bT = b * 2048;
  const int qtA = 31 - p, qtB = p;
  ushort_t* PwA = Ps[wave];
  ushort_t* PwB = Ps[wave + 4];

  auto stage = [&](int kt, int bsel) {
    int k0 = kt * 64;
#pragma unroll
    for (int i = 0; i < 2; ++i) {
      int ci = i * 256 + tid;
      int row = ci >> 3, ch = (ci & 7) ^ (row & 7);
      async_ld16(qk + (size_t)(bT + k0 + row) * 2048 + 1024 + h * 64 + ch * 8,
                 Kb[bsel] + (i * 256 + wave * 64) * 8);
      async_ld16(vt + (size_t)(bh * 64 + row) * 2048 + k0 + ch * 8,
                 Vb[bsel] + (i * 256 + wave * 64) * 8);
    }
  };

  // Q tiles -> dedicated buffers, then K/V stages 0,1
#pragma unroll
  for (int i = 0; i < 2; ++i) {
    int ci = i * 256 + tid;
    int row = ci >> 3, ch = (ci & 7) ^ (row & 7);
    async_ld16(qk + (size_t)(bT + qtA * 64 + row) * 2048 + h * 64 + ch * 8,
               Qa + (i * 256 + wave * 64) * 8);
    async_ld16(qk + (size_t)(bT + qtB * 64 + row) * 2048 + h * 64 + ch * 8,
               Qb + (i * 256 + wave * 64) * 8);
  }
  stage(0, 0);
  stage(1, 1);
  waitcnt_barrier<0x0F78>();  // vmcnt(8): the 4 Q loads (oldest) are done
  bf16x8 qfA[2], qfB[2];
#pragma unroll
  for (int ks = 0; ks < 2; ++ks) {
    int off = (wave * 16 + l16) * 64 + (((ks * 4 + quad) ^ r7) * 8);
    qfA[ks] = *(const bf16x8*)(Qa + off);
    qfB[ks] = *(const bf16x8*)(Qb + off);
  }

  f32x4 oA[4] = {}, oB[4] = {};
  float lA = 0.f, lB = 0.f;

  const int KT = qtA + 1;
  for (int kt = 0; kt < KT; ++kt) {
    waitcnt_barrier<0x0F74>();  // vmcnt(4): stage(kt) landed, (kt+1) in flight
    if (kt + 2 < KT) stage(kt + 2, (kt + 2) % 3);
    const ushort_t* Kc = Kb[kt % 3];
    const ushort_t* Vc = Vb[kt % 3];
    const bool doB = (kt <= qtB);

    // shared K fragments
    bf16x8 kf[4][2];
#pragma unroll
    for (int j = 0; j < 4; ++j)
#pragma unroll
      for (int ks = 0; ks < 2; ++ks)
        kf[j][ks] = *(const bf16x8*)(Kc + (j * 16 + l16) * 64 + (((ks * 4 + quad) ^ r7) * 8));
    // S for A and B (independent chains, interleavable by scheduler)
    f32x4 sA[4] = {}, sB[4] = {};
#pragma unroll
    for (int ks = 0; ks < 2; ++ks)
#pragma unroll
      for (int j = 0; j < 4; ++j)
        sA[j] = __builtin_amdgcn_mfma_f32_16x16x32_bf16(kf[j][ks], qfA[ks], sA[j], 0, 0, 0);
    if (doB)
#pragma unroll
      for (int ks = 0; ks < 2; ++ks)
#pragma unroll
        for (int j = 0; j < 4; ++j)
          sB[j] = __builtin_amdgcn_mfma_f32_16x16x32_bf16(kf[j][ks], qfB[ks], sB[j], 0, 0, 0);
    // causal masks on diagonal tiles
    int qloc = wave * 16 + l16;
    if (kt == qtA)
#pragma unroll
      for (int j = 0; j < 4; ++j)
#pragma unroll
        for (int r = 0; r < 4; ++r)
          if (j * 16 + quad * 4 + r > qloc) sA[j][r] = -1e30f;
    if (kt == qtB)
#pragma unroll
      for (int j = 0; j < 4; ++j)
#pragma unroll
        for (int r = 0; r < 4; ++r)
          if (j * 16 + quad * 4 + r > qloc) sB[j][r] = -1e30f;
    // static-max softmax + P^T pack -> wave-private LDS (both tiles)
#pragma unroll
    for (int j = 0; j < 4; ++j) {
#pragma unroll
      for (int r = 0; r < 4; ++r) {
        float pv = exp2f(sA[j][r]);
        sA[j][r] = pv;
        lA += pv;
      }
      uint2 pp;
      pp.x = pk_bf(sA[j][0], sA[j][1]);
      pp.y = pk_bf(sA[j][2], sA[j][3]);
      *(uint2*)(PwA + l16 * 72 + j * 16 + quad * 4) = pp;
    }
    if (doB)
#pragma unroll
      for (int j = 0; j < 4; ++j) {
#pragma unroll
        for (int r = 0; r < 4; ++r) {
          float pv = exp2f(sB[j][r]);
          sB[j][r] = pv;
          lB += pv;
        }
        uint2 pp;
        pp.x = pk_bf(sB[j][0], sB[j][1]);
        pp.y = pk_bf(sB[j][2], sB[j][3]);
        *(uint2*)(PwB + l16 * 72 + j * 16 + quad * 4) = pp;
      }
    __builtin_amdgcn_s_waitcnt(0xc07f);  // ONE lgkmcnt(0) for both tiles
    // V fragments + both PV accumulations
    bf16x8 pfA[2], pfB[2];
#pragma unroll
    for (int ks = 0; ks < 2; ++ks) {
      pfA[ks] = *(const bf16x8*)(PwA + l16 * 72 + ks * 32 + quad * 8);
      pfB[ks] = *(const bf16x8*)(PwB + l16 * 72 + ks * 32 + quad * 8);
    }
#pragma unroll
    for (int ks = 0; ks < 2; ++ks)
#pragma unroll
      for (int j = 0; j < 4; ++j) {
        bf16x8 vf = *(const bf16x8*)(Vc + (j * 16 + l16) * 64 + (((ks * 4 + quad) ^ r7) * 8));
        oA[j] = __builtin_amdgcn_mfma_f32_16x16x32_bf16(vf, pfA[ks], oA[j], 0, 0, 0);
        if (doB)
          oB[j] = __builtin_amdgcn_mfma_f32_16x16x32_bf16(vf, pfB[ks], oB[j], 0, 0, 0);
      }
  }

  auto wrt = [&](int qt, f32x4* o, float l) {
    l += __shfl_xor(l, 16, 64);
    l += __shfl_xor(l, 32, 64);
    float inv = 1.f / l;
    size_t row = (size_t)(bT + qt * 64 + wave * 16 + l16);
#pragma unroll
    for (int j = 0; j < 4; ++j) {
      uint2 pp;
      pp.x = pk_bf(o[j][0] * inv, o[j][1] * inv);
      pp.y = pk_bf(o[j][2] * inv, o[j][3] * inv);
      *(uint2*)(y + row * 1024 + h * 64 + j * 16 + quad * 4) = pp;
    }
  };
  wrt(qtA, oA, lA);
  wrt(qtB, oB, lB);
}

extern "C" void kernel_launch(void* const* d_in, const int* in_sizes, int n_in,
                              void* d_out, int out_size, void* d_ws, size_t ws_size,
                              hipStream_t stream) {
  const float* x  = (const float*)d_in[0];
  const float* Wa = (const float*)d_in[1];
  const float* ba = (const float*)d_in[2];
  const float* Wp = (const float*)d_in[3];
  const float* bp = (const float*)d_in[4];
  float* out = (float*)d_out;
  char* ws = (char*)d_ws;
  // ws layout (bytes): xb 8.39M | Wab 6.29M | Wpb 2.10M | qk 16.78M | yb 8.39M | vt 8.39M
  ushort_t* xb  = (ushort_t*)(ws);
  ushort_t* Wab = (ushort_t*)(ws + 8388608);
  ushort_t* Wpb = (ushort_t*)(ws + 14680064);
  ushort_t* qkb = (ushort_t*)(ws + 16777216);
  ushort_t* yb  = (ushort_t*)(ws + 33554432);
  ushort_t* vtb = (ushort_t*)(ws + 41943040);

  cvt_all<<<8192, 256, 0, stream>>>(x, Wa, Wp, xb, Wab, Wpb);
  // qkv = x @ W_attn^T + b_attn; Q scaled by 0.125*log2(e); V written transposed
  // 512 threads -> 24 waves/CU at 3 blocks/CU
  gemm_bt<128, 128, 4, 2, 1, 512><<<dim3(24, 32), 512, 0, stream>>>(
      xb, Wab, ba, nullptr, qkb, vtb, 4096, 3072, 1024, 2048, 0.18033688011112042f);
  // flash attention -> yb [4096,1024] bf16 (fused pair per block)
  flash4<<<dim3(16, 32), 256, 0, stream>>>(qkb, vtb, yb);
  // out = yb @ W_proj^T + b_proj  [4096,1024] f32  (64x64 tiles -> 1024 blocks)
  gemm_bt<64, 64, 2, 2, 0, 256><<<dim3(16, 64), 256, 0, stream>>>(
      yb, Wpb, bp, out, nullptr, nullptr, 4096, 1024, 1024, 1024, 1.0f);
}

// Round 8
// 199.759 us; speedup vs baseline: 1.8889x; 1.1975x over previous
//
#include <hip/hip_runtime.h>

typedef unsigned short ushort_t;
typedef __bf16 bf16x8 __attribute__((ext_vector_type(8)));
typedef float f32x4 __attribute__((ext_vector_type(4)));

// f32 -> bf16 bits, round-to-nearest-even
__device__ inline ushort_t f2bf(float f) {
  unsigned int u = __builtin_bit_cast(unsigned int, f);
  u += 0x7fff + ((u >> 16) & 1);
  return (ushort_t)(u >> 16);
}

// pack two f32 -> bf16x2 (RNE), b in high half
__device__ inline unsigned pk_bf(float a, float b) {
  unsigned ua = __builtin_bit_cast(unsigned, a);
  unsigned ub = __builtin_bit_cast(unsigned, b);
  ua += 0x7fff + ((ua >> 16) & 1);
  ub += 0x7fff + ((ub >> 16) & 1);
  return __builtin_amdgcn_perm(ub, ua, 0x07060302);
}

// async global->LDS, 16B per lane; LDS dest = wave-uniform base + lane*16B
__device__ inline void async_ld16(const ushort_t* g, const ushort_t* l) {
  __builtin_amdgcn_global_load_lds(
      (const __attribute__((address_space(1))) void*)g,
      (__attribute__((address_space(3))) void*)l, 16, 0, 0);
}

// vmcnt(N) wait + workgroup barrier. IMM: 0x0F70|N (lgkm=15, exp=7 -> no wait)
template <int IMM>
__device__ inline void waitcnt_barrier() {
  asm volatile("" ::: "memory");
  __builtin_amdgcn_s_waitcnt(IMM);
  __builtin_amdgcn_s_barrier();
  asm volatile("" ::: "memory");
}

// one fused conversion kernel: x (1048576 f4) | Wa (786432 f4) | Wp (262144 f4)
__global__ void cvt_all(const float* __restrict__ x, const float* __restrict__ wa,
                        const float* __restrict__ wp, ushort_t* __restrict__ xb,
                        ushort_t* __restrict__ wab, ushort_t* __restrict__ wpb) {
  int i = blockIdx.x * 256 + threadIdx.x;
  const float* src;
  ushort_t* dst;
  int off;
  if (i < 1048576) { src = x; dst = xb; off = i; }
  else if (i < 1835008) { src = wa; dst = wab; off = i - 1048576; }
  else { src = wp; dst = wpb; off = i - 1835008; }
  float4 f = ((const float4*)src)[off];
  unsigned long long p = (unsigned long long)f2bf(f.x)
      | ((unsigned long long)f2bf(f.y) << 16)
      | ((unsigned long long)f2bf(f.z) << 32)
      | ((unsigned long long)f2bf(f.w) << 48);
  ((unsigned long long*)dst)[off] = p;
}

// C[m][n] = sum_k A[m][k]*B[n][k] + bias[n]; A:[M,K] bf16, B:[N,K] bf16.
// BK=32, TRIPLE-buffered LDS, depth-2 prefetch, manual vmcnt barriers.
template <int BM, int BN, int IM, int JN, int MODE, int TPB>
__global__ __launch_bounds__(TPB) void gemm_bt(
    const ushort_t* __restrict__ A, const ushort_t* __restrict__ B,
    const float* __restrict__ bias, float* __restrict__ Cf,
    ushort_t* __restrict__ Cb, ushort_t* __restrict__ vtb,
    int M, int N, int K, int ldc, float qscale) {
  constexpr int NWN = BN / (JN * 16);
  constexpr int NL = (BM + BN) * 32 / (TPB * 8);  // vmem loads/thread/stage
  constexpr int WIMM = 0x0F70 | NL;               // vmcnt(NL)
  __shared__ __align__(16) ushort_t As[3][BM * 32];
  __shared__ __align__(16) ushort_t Bs[3][BN * 32];
  const int tid = threadIdx.x;
  const int wave = tid >> 6, lane = tid & 63;
  const int quad = lane >> 4, l16 = lane & 15;
  const int wr = wave / NWN, wc = wave % NWN;
  const int wm = wr * IM * 16, wn = wc * JN * 16;
  const int m0 = blockIdx.y * BM, n0 = blockIdx.x * BN;
  const ushort_t* Ag = A + (size_t)m0 * K;
  const ushort_t* Bg = B + (size_t)n0 * K;
  const int slot = (quad ^ ((l16 >> 1) & 3)) * 8;
  f32x4 acc[IM][JN] = {};

  auto stage = [&](int kt, int bsel) {
    int k0 = kt * 32;
#pragma unroll
    for (int p = 0; p < BM * 4 / TPB; ++p) {
      int ci = p * TPB + tid;
      int row = ci >> 2, ch = (ci & 3) ^ ((ci >> 3) & 3);
      async_ld16(Ag + (size_t)row * K + k0 + ch * 8, As[bsel] + (p * TPB + wave * 64) * 8);
    }
#pragma unroll
    for (int p = 0; p < BN * 4 / TPB; ++p) {
      int ci = p * TPB + tid;
      int row = ci >> 2, ch = (ci & 3) ^ ((ci >> 3) & 3);
      async_ld16(Bg + (size_t)row * K + k0 + ch * 8, Bs[bsel] + (p * TPB + wave * 64) * 8);
    }
  };

  const int KT = K / 32;
  stage(0, 0);
  stage(1, 1);
  for (int kt = 0; kt < KT; ++kt) {
    waitcnt_barrier<WIMM>();  // stage(kt) landed; stage(kt+1) still in flight
    if (kt + 2 < KT) stage(kt + 2, (kt + 2) % 3);
    const ushort_t* Ac = As[kt % 3];
    const ushort_t* Bc = Bs[kt % 3];
    bf16x8 af[IM], bfr[JN];
#pragma unroll
    for (int i = 0; i < IM; ++i)
      af[i] = *(const bf16x8*)(Ac + (wm + i * 16 + l16) * 32 + slot);
#pragma unroll
    for (int j = 0; j < JN; ++j)
      bfr[j] = *(const bf16x8*)(Bc + (wn + j * 16 + l16) * 32 + slot);
#pragma unroll
    for (int i = 0; i < IM; ++i)
#pragma unroll
      for (int j = 0; j < JN; ++j)
        acc[i][j] = __builtin_amdgcn_mfma_f32_16x16x32_bf16(af[i], bfr[j], acc[i][j], 0, 0, 0);
  }

  if (MODE == 1 && n0 >= 2048) {
    // V third: write transposed packed to vtb[(b*16+h)*64+d][t]
#pragma unroll
    for (int j = 0; j < JN; ++j) {
      int col = n0 + wn + j * 16 + l16;
      int cv = col - 2048;
      float bv = bias[col];
      size_t rowbase = ((size_t)(cv >> 6)) * 64 + (cv & 63);  // (h*64+d) within batch
#pragma unroll
      for (int i = 0; i < IM; ++i) {
        int rowb = m0 + wm + i * 16 + quad * 4;
        int bb = rowb >> 11, t = rowb & 2047;
        uint2 pp;
        pp.x = pk_bf(acc[i][j][0] + bv, acc[i][j][1] + bv);
        pp.y = pk_bf(acc[i][j][2] + bv, acc[i][j][3] + bv);
        *(uint2*)(vtb + (((size_t)bb * 1024 + rowbase) * 2048 + t)) = pp;
      }
    }
    return;
  }
#pragma unroll
  for (int j = 0; j < JN; ++j) {
    int col = n0 + wn + j * 16 + l16;
    float bv = bias[col];
    float sc = (MODE == 1 && col < 1024) ? qscale : 1.0f;
#pragma unroll
    for (int i = 0; i < IM; ++i)
#pragma unroll
      for (int r = 0; r < 4; ++r) {
        int row = m0 + wm + i * 16 + quad * 4 + r;
        float v = (acc[i][j][r] + bv) * sc;
        if (MODE == 1)
          Cb[(size_t)row * ldc + col] = f2bf(v);
        else
          Cf[(size_t)row * ldc + col] = v;
      }
  }
}

// Chunked transposed flash attention, causal, exp2 basis, static max.
// Static max => O and l are PURE SUMS over k-tiles => k-range splittable
// across blocks, combined exactly afterwards. Chunk map per bh (48 blocks):
//   x in [0,16):  qt=31-x,      k [0, h)      -> partial to ob0 (h=(qt+2)/2)
//   x in [16,32): qt=31-(x-16), k [h, qt+1)   -> partial to ob1 (has diagonal)
//   x in [32,48): qt=47-x (15..0), k [0,qt+1) -> direct yb write
// Q direct global->regs; K/V double-buffered LDS; Ps wave-private.
// LDS 41984 B -> 3 blocks/CU; phase-drifting blocks hide chain stalls.
__global__ __launch_bounds__(256, 3) void flash5(
    const ushort_t* __restrict__ qk, const ushort_t* __restrict__ vt,
    ushort_t* __restrict__ y, float* __restrict__ ob0, float* __restrict__ ob1,
    float* __restrict__ lb0, float* __restrict__ lb1) {
  __shared__ __align__(16) ushort_t Kb[2][4096];
  __shared__ __align__(16) ushort_t Vb[2][4096];
  __shared__ __align__(16) ushort_t Ps[4][1152];
  const int tid = threadIdx.x, wave = tid >> 6, lane = tid & 63;
  const int quad = lane >> 4, l16 = lane & 15;
  const int r7 = l16 & 7;
  const int x = blockIdx.x, bh = blockIdx.y;
  const int b = bh >> 4, h = bh & 15;
  const int bT = b * 2048;
  int qt, klo, khi, mode;
  if (x < 16)      { qt = 31 - x;        klo = 0;            khi = (qt + 2) / 2; mode = 1; }
  else if (x < 32) { qt = 31 - (x - 16); klo = (qt + 2) / 2; khi = qt + 1;       mode = 2; }
  else             { qt = 47 - x;        klo = 0;            khi = qt + 1;       mode = 0; }
  ushort_t* Pw = Ps[wave];

  // Q B-fragments straight from global (one-time read, L2-hot)
  const ushort_t* qrow = qk + (size_t)(bT + qt * 64 + wave * 16 + l16) * 2048 + h * 64 + quad * 8;
  bf16x8 qf[2];
  qf[0] = *(const bf16x8*)(qrow);
  qf[1] = *(const bf16x8*)(qrow + 32);

  auto stage = [&](int kt, int bsel) {
    int k0 = kt * 64;
#pragma unroll
    for (int i = 0; i < 2; ++i) {
      int ci = i * 256 + tid;
      int row = ci >> 3, ch = (ci & 7) ^ (row & 7);
      async_ld16(qk + (size_t)(bT + k0 + row) * 2048 + 1024 + h * 64 + ch * 8,
                 Kb[bsel] + (i * 256 + wave * 64) * 8);
      async_ld16(vt + (size_t)(bh * 64 + row) * 2048 + k0 + ch * 8,
                 Vb[bsel] + (i * 256 + wave * 64) * 8);
    }
  };

  f32x4 o[4] = {};
  float l = 0.f;

  stage(klo, 0);
  for (int kt = klo; kt < khi; ++kt) {
    const int cur = (kt - klo) & 1;
    waitcnt_barrier<0x0F70>();  // vmcnt(0): stage(kt) landed; buf cur^1 free
    if (kt + 1 < khi) stage(kt + 1, cur ^ 1);
    const ushort_t* Kc = Kb[cur];
    const ushort_t* Vc = Vb[cur];
    f32x4 s[4] = {};
#pragma unroll
    for (int ks = 0; ks < 2; ++ks)
#pragma unroll
      for (int j = 0; j < 4; ++j) {
        bf16x8 kf = *(const bf16x8*)(Kc + (j * 16 + l16) * 64 + (((ks * 4 + quad) ^ r7) * 8));
        s[j] = __builtin_amdgcn_mfma_f32_16x16x32_bf16(kf, qf[ks], s[j], 0, 0, 0);
      }
    if (kt == qt) {  // diagonal tile (mode 0 or 2 only)
      int qloc = wave * 16 + l16;
#pragma unroll
      for (int j = 0; j < 4; ++j)
#pragma unroll
        for (int r = 0; r < 4; ++r)
          if (j * 16 + quad * 4 + r > qloc) s[j][r] = -1e30f;
    }
    // static-max softmax: P = exp2(s); per-lane partial row-sum
#pragma unroll
    for (int j = 0; j < 4; ++j) {
#pragma unroll
      for (int r = 0; r < 4; ++r) {
        float pv = exp2f(s[j][r]);
        s[j][r] = pv;
        l += pv;
      }
      uint2 pp;
      pp.x = pk_bf(s[j][0], s[j][1]);
      pp.y = pk_bf(s[j][2], s[j][3]);
      *(uint2*)(Pw + l16 * 72 + j * 16 + quad * 4) = pp;
    }
    __builtin_amdgcn_s_waitcnt(0xc07f);  // lgkmcnt(0): own-wave P visibility
    bf16x8 pf[2];
    pf[0] = *(const bf16x8*)(Pw + l16 * 72 + quad * 8);
    pf[1] = *(const bf16x8*)(Pw + l16 * 72 + 32 + quad * 8);
#pragma unroll
    for (int ks = 0; ks < 2; ++ks)
#pragma unroll
      for (int j = 0; j < 4; ++j) {
        bf16x8 vf = *(const bf16x8*)(Vc + (j * 16 + l16) * 64 + (((ks * 4 + quad) ^ r7) * 8));
        o[j] = __builtin_amdgcn_mfma_f32_16x16x32_bf16(vf, pf[ks], o[j], 0, 0, 0);
      }
  }

  // reduce l across the 4 quads holding the same q
  l += __shfl_xor(l, 16, 64);
  l += __shfl_xor(l, 32, 64);
  if (mode == 0) {
    float inv = 1.f / l;
    size_t row = (size_t)(bT + qt * 64 + wave * 16 + l16);
#pragma unroll
    for (int j = 0; j < 4; ++j) {
      uint2 pp;
      pp.x = pk_bf(o[j][0] * inv, o[j][1] * inv);
      pp.y = pk_bf(o[j][2] * inv, o[j][3] * inv);
      *(uint2*)(y + row * 1024 + h * 64 + j * 16 + quad * 4) = pp;
    }
  } else {
    float* ob = (mode == 1) ? ob0 : ob1;
    float* lb = (mode == 1) ? lb0 : lb1;
    size_t base = (((size_t)bh * 16 + (qt - 16)) * 64 + wave * 16 + l16) * 64;
#pragma unroll
    for (int j = 0; j < 4; ++j)
      *(f32x4*)(ob + base + j * 16 + quad * 4) = o[j];
    if (quad == 0)
      lb[((size_t)bh * 16 + (qt - 16)) * 64 + wave * 16 + l16] = l;
  }
}

// combine partials for qt>=16: y = (O0+O1)/(l0+l1), bf16
__global__ void combine(const float* __restrict__ ob0, const float* __restrict__ ob1,
                        const float* __restrict__ lb0, const float* __restrict__ lb1,
                        ushort_t* __restrict__ y) {
  int id = blockIdx.x * 256 + threadIdx.x;   // [32 bh][16 qx][64 q][16 dg]
  int dg = id & 15, q = (id >> 4) & 63, qx = (id >> 10) & 15, bh = id >> 14;
  size_t po = (((size_t)bh * 16 + qx) * 64 + q) * 64 + dg * 4;
  float4 a = *(const float4*)(ob0 + po);
  float4 c = *(const float4*)(ob1 + po);
  size_t pl = ((size_t)bh * 16 + qx) * 64 + q;
  float inv = 1.f / (lb0[pl] + lb1[pl]);
  uint2 pp;
  pp.x = pk_bf((a.x + c.x) * inv, (a.y + c.y) * inv);
  pp.y = pk_bf((a.z + c.z) * inv, (a.w + c.w) * inv);
  size_t row = (size_t)((bh >> 4) * 2048 + (16 + qx) * 64 + q);
  *(uint2*)(y + row * 1024 + (bh & 15) * 64 + dg * 4) = pp;
}

extern "C" void kernel_launch(void* const* d_in, const int* in_sizes, int n_in,
                              void* d_out, int out_size, void* d_ws, size_t ws_size,
                              hipStream_t stream) {
  const float* x  = (const float*)d_in[0];
  const float* Wa = (const float*)d_in[1];
  const float* ba = (const float*)d_in[2];
  const float* Wp = (const float*)d_in[3];
  const float* bp = (const float*)d_in[4];
  float* out = (float*)d_out;
  char* ws = (char*)d_ws;
  // ws: xb 8.39M | Wab 6.29M | Wpb 2.10M | qk 16.78M | yb 8.39M | vt 8.39M
  // xb+Wab region [0,14.68M) is dead after the QKV GEMM -> reused by flash
  // partials: ob1 8.39M at 0, lb0/lb1 at 8.39M. ob0 = d_out (free until proj).
  ushort_t* xb  = (ushort_t*)(ws);
  ushort_t* Wab = (ushort_t*)(ws + 8388608);
  ushort_t* Wpb = (ushort_t*)(ws + 14680064);
  ushort_t* qkb = (ushort_t*)(ws + 16777216);
  ushort_t* yb  = (ushort_t*)(ws + 33554432);
  ushort_t* vtb = (ushort_t*)(ws + 41943040);
  float* ob0 = (float*)d_out;
  float* ob1 = (float*)(ws);
  float* lb0 = (float*)(ws + 8388608);
  float* lb1 = (float*)(ws + 8519680);

  cvt_all<<<8192, 256, 0, stream>>>(x, Wa, Wp, xb, Wab, Wpb);
  // qkv = x @ W_attn^T + b_attn; Q scaled by 0.125*log2(e); V written transposed
  gemm_bt<128, 128, 4, 2, 1, 512><<<dim3(24, 32), 512, 0, stream>>>(
      xb, Wab, ba, nullptr, qkb, vtb, 4096, 3072, 1024, 2048, 0.18033688011112042f);
  // chunked flash attention (1536 uniform-ish blocks, 3 blocks/CU)
  flash5<<<dim3(48, 32), 256, 0, stream>>>(qkb, vtb, yb, ob0, ob1, lb0, lb1);
  // combine partials for qt>=16 rows
  combine<<<2048, 256, 0, stream>>>(ob0, ob1, lb0, lb1, yb);
  // out = yb @ W_proj^T + b_proj  [4096,1024] f32
  gemm_bt<64, 64, 2, 2, 0, 256><<<dim3(16, 64), 256, 0, stream>>>(
      yb, Wpb, bp, out, nullptr, nullptr, 4096, 1024, 1024, 1024, 1.0f);
}